// Round 1
// baseline (14516.635 us; speedup 1.0000x reference)
//
#include <hip/hip_runtime.h>
#include <math.h>

#define NB   128   // batch
#define SEQ  512   // sequence length
#define HD   128   // hidden
#define NCL  16    // clusters C
#define NOUT 8     // classes
#define CIN  260   // 2H+4
#define FEPS 1e-4f
#define HP   132   // padded row stride for centers (bank-conflict pad)

__device__ __forceinline__ float red16(float v){
    v += __shfl_xor(v, 1, 16); v += __shfl_xor(v, 2, 16);
    v += __shfl_xor(v, 4, 16); v += __shfl_xor(v, 8, 16);
    return v;
}
__device__ __forceinline__ float max16(float v){
    v = fmaxf(v, __shfl_xor(v, 1, 16)); v = fmaxf(v, __shfl_xor(v, 2, 16));
    v = fmaxf(v, __shfl_xor(v, 4, 16)); v = fmaxf(v, __shfl_xor(v, 8, 16));
    return v;
}
__device__ __forceinline__ float red64(float v){
    v += __shfl_xor(v, 1, 64); v += __shfl_xor(v, 2, 64); v += __shfl_xor(v, 4, 64);
    v += __shfl_xor(v, 8, 64); v += __shfl_xor(v,16, 64); v += __shfl_xor(v,32, 64);
    return v;
}
__device__ __forceinline__ float sigm(float x){ return 1.f/(1.f + expf(-x)); }
__device__ __forceinline__ float softplusf(float x){ return log1pf(expf(-fabsf(x))) + fmaxf(x, 0.f); }

__global__ __launch_bounds__(512)
void cfrm_kernel(const int*  __restrict__ tokens,
                 const float* __restrict__ emb,
                 const float* __restrict__ ln_g, const float* __restrict__ ln_b,
                 const float* __restrict__ w1,   const float* __restrict__ b1,
                 const float* __restrict__ w2,   const float* __restrict__ b2,
                 const float* __restrict__ gate_w, const float* __restrict__ gate_b,
                 const float* __restrict__ assign_w, const float* __restrict__ assign_b,
                 const float* __restrict__ nov_w, const float* __restrict__ nov_b,
                 const float* __restrict__ relax_w, const float* __restrict__ relax_b,
                 const float* __restrict__ cc_w, const float* __restrict__ cc_b,
                 const float* __restrict__ cs_w, const float* __restrict__ cs_b,
                 const float* __restrict__ md_w, const float* __restrict__ md_b,
                 const float* __restrict__ att_w, const float* __restrict__ att_b,
                 const float* __restrict__ cw1,  const float* __restrict__ cb1,
                 const float* __restrict__ cw2,  const float* __restrict__ cb2,
                 float* __restrict__ out)
{
    const int bidx = blockIdx.x;
    const int tid  = threadIdx.x;
    const int lane = tid & 63;
    const int wv   = tid >> 6;

    __shared__ float s_centers[NCL][HP];
    __shared__ float s_mc[NCL][HP];        // gram (16x16 corner), then mixed centers
    __shared__ float s_ci[CIN];            // [token(128) | core(128) | u,d,en,ent]
    __shared__ float s_ctrl1[HD];
    __shared__ float s_ctrl[HD];
    __shared__ float s_red[4][HD];
    __shared__ float s_hred[4][NCL];
    __shared__ float s_att[HD];
    __shared__ float s_mix[NCL][NCL];
    __shared__ float s_alpha[NCL];
    __shared__ float s_spreads[NCL], s_masses[NCL];
    __shared__ float s_ss[NCL], s_cands[NCL], s_mdl[NCL];
    __shared__ float s_ms[NCL], s_mm[NCL];
    __shared__ float s_scal[4];            // [0]=novelty, [1]=relax
    __shared__ int   s_ibest;

    // ---- init state ----
    for (int i = tid; i < NCL*HP; i += 512) ((float*)s_centers)[i] = 0.f;
    if (tid < NCL){ s_spreads[tid] = 1.f; s_masses[tid] = 0.f; }
    __syncthreads();

    for (int s = 0; s < SEQ; ++s){
        const int tok = tokens[bidx*SEQ + s];
        const float valid = (tok != 0) ? 1.f : 0.f;

        // ---- phase 1: token embed + LayerNorm (wave 0) ----
        if (wv == 0){
            float e0 = emb[(size_t)tok*HD + lane];
            float e1 = emb[(size_t)tok*HD + 64 + lane];
            float sm = red64(e0 + e1);
            float sq = red64(e0*e0 + e1*e1);
            float mu  = sm * (1.f/128.f);
            float var = sq * (1.f/128.f) - mu*mu;
            float inv = 1.f / sqrtf(var + 1e-5f);
            s_ci[lane]      = (e0 - mu)*inv*ln_g[lane]      + ln_b[lane];
            s_ci[64 + lane] = (e1 - mu)*inv*ln_g[64 + lane] + ln_b[64 + lane];
        }
        // ---- phase 2a: cluster scores / alpha / u,en,ent (wave 1, lanes 0-15) ----
        if (wv == 1 && lane < NCL){
            float sp = s_spreads[lane], ma = s_masses[lane];
            float prec = 1.f/(sp + FEPS);
            float sc = ma + logf(prec + FEPS);
            float mx = max16(sc);
            float ex = expf(sc - mx);
            float smn = red16(ex);
            float al = ex / smn;
            s_alpha[lane] = al;
            float u = red16(al * sp);
            float mmx = max16(ma);
            float es = red16(expf(ma - mmx));
            float en = mmx + logf(es);
            float ent = -red16(al * logf(fmaxf(al, 1e-8f)));
            if (lane == 0){ s_ci[256] = u; s_ci[258] = en; s_ci[259] = ent; }
        }
        __syncthreads();  // B1

        // ---- phase 2b: core ----
        if (tid < HD){
            float acc = 0.f;
            #pragma unroll
            for (int c = 0; c < NCL; ++c) acc += s_alpha[c] * s_centers[c][tid];
            s_ci[128 + tid] = acc;
        }
        __syncthreads();  // B2

        // ---- phase 2c: diversity (wave 0) ----
        if (wv == 0){
            int c = lane >> 2, p = lane & 3;
            float acc = 0.f;
            #pragma unroll 8
            for (int hh = p*32; hh < p*32 + 32; ++hh){
                float d = s_centers[c][hh] - s_ci[128 + hh];
                acc += d*d;
            }
            acc += __shfl_xor(acc, 1, 4); acc += __shfl_xor(acc, 2, 4);
            float v = ((lane & 3) == 0) ? s_alpha[c]*acc*(1.f/128.f) : 0.f;
            v = red64(v);
            if (lane == 0) s_ci[257] = v;
        }
        __syncthreads();  // B3

        // ---- phase 3: ctrl1 = tanh(ci @ w1 + b1), 260x128 ----
        {
            int j = tid & 127, part = tid >> 7;
            int k0 = part*65;
            float acc = 0.f;
            for (int k = k0; k < k0 + 65; ++k) acc += s_ci[k] * w1[k*HD + j];
            s_red[part][j] = acc;
        }
        __syncthreads();  // B4
        if (tid < HD)
            s_ctrl1[tid] = tanhf(b1[tid] + s_red[0][tid] + s_red[1][tid] + s_red[2][tid] + s_red[3][tid]);
        __syncthreads();  // B5

        // ---- phase 4: ctrl = tanh(ctrl1 @ w2 + b2), 128x128 ----
        {
            int j = tid & 127, part = tid >> 7;
            int k0 = part*32;
            float acc = 0.f;
            #pragma unroll 8
            for (int kk = 0; kk < 32; ++kk){ int k = k0 + kk; acc += s_ctrl1[k] * w2[k*HD + j]; }
            s_red[part][j] = acc;
        }
        __syncthreads();  // B6
        if (tid < HD)
            s_ctrl[tid] = tanhf(b2[tid] + s_red[0][tid] + s_red[1][tid] + s_red[2][tid] + s_red[3][tid]);
        __syncthreads();  // B7

        // ---- phase 5+6 partials: heads (gate/assign/cs/md) + attractor ----
        {
            int head = tid >> 7, c = (tid >> 3) & 15, part = tid & 7;
            const float* hw = (head == 0) ? gate_w : (head == 1) ? assign_w : (head == 2) ? cs_w : md_w;
            int k0 = part*16;
            float acc = 0.f;
            #pragma unroll
            for (int kk = 0; kk < 16; ++kk){ int k = k0 + kk; acc += s_ctrl[k] * hw[k*NCL + c]; }
            acc += __shfl_xor(acc, 1, 8); acc += __shfl_xor(acc, 2, 8); acc += __shfl_xor(acc, 4, 8);
            if (part == 0) s_hred[head][c] = acc;
        }
        {
            int j = tid & 127, part = tid >> 7;
            int k0 = part*32;
            float acc = 0.f;
            #pragma unroll 8
            for (int kk = 0; kk < 32; ++kk){ int k = k0 + kk; acc += s_ctrl[k] * att_w[k*HD + j]; }
            s_red[part][j] = acc;
        }
        __syncthreads();  // B8

        // ---- phase 5+6 finals ----
        if (tid < HD){
            s_att[tid] = att_b[tid] + s_red[0][tid] + s_red[1][tid] + s_red[2][tid] + s_red[3][tid];
        } else if (tid < 192 && lane < NCL){       // wave 2, lanes 0-15
            int c = lane;
            float g    = sigm(s_hred[0][c] + gate_b[c]) * valid;
            float araw = s_hred[1][c] + assign_b[c];
            float mx = max16(araw);
            float ex = expf(araw - mx);
            float smn = red16(ex);
            s_ss[c]   = g * (ex / smn);
            s_cands[c] = softplusf(s_hred[2][c] + cs_b[c]) + FEPS;
            s_mdl[c]  = tanhf(s_hred[3][c] + md_b[c]);
        } else if (tid >= 192 && tid < 256){       // wave 3: novelty / relax
            float c0 = s_ctrl[lane], c1 = s_ctrl[64 + lane];
            float np = red64(c0*nov_w[lane]   + c1*nov_w[64 + lane]);
            float rp = red64(c0*relax_w[lane] + c1*relax_w[64 + lane]);
            if (lane == 0){
                s_scal[0] = sigm(np + nov_b[0])   * valid;
                s_scal[1] = sigm(rp + relax_b[0]) * valid;
            }
        }
        __syncthreads();  // B9

        // ---- phase 7: cand centers (ctrl @ cc_w), state update, attractor ----
        {
            int j0 = tid*4;
            int c = j0 >> 7, h = j0 & 127;
            float a0 = 0.f, a1 = 0.f, a2 = 0.f, a3 = 0.f;
            const float* wp = cc_w + j0;
            for (int k = 0; k < HD; ++k){
                float cl = s_ctrl[k];
                float4 w = *(const float4*)(wp + (k << 11));
                a0 += cl*w.x; a1 += cl*w.y; a2 += cl*w.z; a3 += cl*w.w;
            }
            float4 cb = *(const float4*)(cc_b + j0);
            float ssc = s_ss[c];
            float nv  = s_scal[0];
            float4 av = *(const float4*)(&s_att[h]);
            float4* cp = (float4*)(&s_centers[c][h]);
            float4 ov = *cp;
            float c0x = ov.x + ssc*((a0 + cb.x) - ov.x); c0x += 0.1f*nv*(av.x - c0x);
            float c1x = ov.y + ssc*((a1 + cb.y) - ov.y); c1x += 0.1f*nv*(av.y - c1x);
            float c2x = ov.z + ssc*((a2 + cb.z) - ov.z); c2x += 0.1f*nv*(av.z - c2x);
            float c3x = ov.w + ssc*((a3 + cb.w) - ov.w); c3x += 0.1f*nv*(av.w - c3x);
            *cp = make_float4(c0x, c1x, c2x, c3x);
        }
        if (tid < NCL){
            float ssc = s_ss[tid];
            s_spreads[tid] += ssc * (s_cands[tid] - s_spreads[tid]);
            s_masses[tid]  += ssc * s_mdl[tid];     // masses += ss*mdelta (NOT delta-to-target)
        }
        __syncthreads();  // B10

        // ---- phase 8a: Gram matrix of centers ----
        if (tid < 256){
            int i = tid >> 4, j = tid & 15;
            const float4* ri = (const float4*)(&s_centers[i][0]);
            const float4* rj = (const float4*)(&s_centers[j][0]);
            float acc = 0.f;
            #pragma unroll 8
            for (int h4 = 0; h4 < 32; ++h4){
                float4 a = ri[h4], bb = rj[h4];
                acc += a.x*bb.x + a.y*bb.y + a.z*bb.z + a.w*bb.w;
            }
            s_mc[i][j] = acc;
        }
        __syncthreads();  // B11

        // ---- phase 8b: compat softmax -> mixing; mixed spreads/masses ----
        if (tid < 256){
            int i = tid >> 4, j = tid & 15;
            float g  = s_mc[i][j];
            float d2 = fmaxf(s_mc[i][i] + s_mc[j][j] - 2.f*g, 0.f);
            float scale = s_spreads[i] + s_spreads[j] + FEPS;
            float cmp = -d2/scale + s_masses[j];
            float mx = max16(cmp);
            float ex = expf(cmp - mx);
            float smn = red16(ex);
            float mix = ex / smn;
            s_mix[i][j] = mix;
            float msp = red16(mix * s_spreads[j]);
            float mma = red16(mix * s_masses[j]);
            if (j == 0){ s_ms[i] = msp; s_mm[i] = mma; }
        }
        __syncthreads();  // B12

        // ---- phase 8c: mixed centers ----
        {
            int j0 = tid*4, i = j0 >> 7, h = j0 & 127;
            float a0 = 0.f, a1 = 0.f, a2 = 0.f, a3 = 0.f;
            #pragma unroll
            for (int j = 0; j < NCL; ++j){
                float m = s_mix[i][j];
                float4 cv = *(const float4*)(&s_centers[j][h]);
                a0 += m*cv.x; a1 += m*cv.y; a2 += m*cv.z; a3 += m*cv.w;
            }
            *(float4*)(&s_mc[i][h]) = make_float4(a0, a1, a2, a3);
        }
        __syncthreads();  // B13

        // ---- phase 8d: relax blend + spread shrink ----
        {
            float rx = s_scal[1];
            int j0 = tid*4, i = j0 >> 7, h = j0 & 127;
            float4* cp = (float4*)(&s_centers[i][h]);
            float4 ov = *cp;
            float4 mv = *(const float4*)(&s_mc[i][h]);
            ov.x = (1.f - rx)*ov.x + rx*mv.x;
            ov.y = (1.f - rx)*ov.y + rx*mv.y;
            ov.z = (1.f - rx)*ov.z + rx*mv.z;
            ov.w = (1.f - rx)*ov.w + rx*mv.w;
            *cp = ov;
            if (tid < NCL){
                float sp = (1.f - rx)*s_spreads[tid] + rx*s_ms[tid];
                float ma = (1.f - rx)*s_masses[tid]  + rx*s_mm[tid];
                float prec = 1.f/(sp + FEPS);
                float sc = ma + logf(prec + FEPS);
                float mx = max16(sc);
                float ex = expf(sc - mx);
                float smn = red16(ex);
                float ca = ex / smn;
                sp = sp*(1.f - 0.05f*ca*valid) + FEPS;
                s_spreads[tid] = sp;
                s_masses[tid]  = ma;
            }
        }
        __syncthreads();  // B14
    }

    // ================= epilogue =================
    if (tid < NCL){
        float sp = s_spreads[tid], ma = s_masses[tid];
        float prec = 1.f/(sp + FEPS);
        float sc = ma + logf(prec + FEPS);
        float mx = max16(sc);
        float ex = expf(sc - mx);
        float smn = red16(ex);
        float al = ex / smn;
        s_alpha[tid] = al;
        float u = red16(al * sp);
        float mmx = max16(ma);
        float es = red16(expf(ma - mmx));
        float en = mmx + logf(es);
        float ent = -red16(al * logf(fmaxf(al, 1e-8f)));
        if (tid == 0){ s_ci[256] = u; s_ci[258] = en; s_ci[259] = ent; }
    }
    __syncthreads();
    if (tid < HD){
        float acc = 0.f;
        #pragma unroll
        for (int c = 0; c < NCL; ++c) acc += s_alpha[c] * s_centers[c][tid];
        s_ci[tid] = acc;   // core -> feats[0:128]
    }
    __syncthreads();
    if (wv == 0){
        int c = lane >> 2, p = lane & 3;
        float acc = 0.f;
        #pragma unroll 8
        for (int hh = p*32; hh < p*32 + 32; ++hh){
            float d = s_centers[c][hh] - s_ci[hh];
            acc += d*d;
        }
        acc += __shfl_xor(acc, 1, 4); acc += __shfl_xor(acc, 2, 4);
        float v = ((lane & 3) == 0) ? s_alpha[c]*acc*(1.f/128.f) : 0.f;
        v = red64(v);
        if (lane == 0) s_ci[257] = v;
    }
    if (wv == 1 && lane == 0){
        int best = 0; float bv = s_alpha[0];
        for (int c = 1; c < NCL; ++c){ if (s_alpha[c] > bv){ bv = s_alpha[c]; best = c; } }
        s_ibest = best;
    }
    __syncthreads();
    if (tid < HD) s_ci[128 + tid] = s_centers[s_ibest][tid];   // strongest
    __syncthreads();
    // classifier layer 1: gelu(feats @ cw1 + cb1)
    {
        int j = tid & 127, part = tid >> 7;
        int k0 = part*65;
        float acc = 0.f;
        for (int k = k0; k < k0 + 65; ++k) acc += s_ci[k] * cw1[k*HD + j];
        s_red[part][j] = acc;
    }
    __syncthreads();
    if (tid < HD){
        float x = cb1[tid] + s_red[0][tid] + s_red[1][tid] + s_red[2][tid] + s_red[3][tid];
        s_ctrl1[tid] = 0.5f*x*(1.f + erff(x*0.70710678118654752f));  // exact gelu
    }
    __syncthreads();
    // classifier layer 2 -> out
    if (tid < 64){
        int n = tid >> 3, p = tid & 7;
        float acc = 0.f;
        #pragma unroll
        for (int kk = 0; kk < 16; ++kk){ int j = p*16 + kk; acc += s_ctrl1[j] * cw2[j*NOUT + n]; }
        acc += __shfl_xor(acc, 1, 8); acc += __shfl_xor(acc, 2, 8); acc += __shfl_xor(acc, 4, 8);
        if (p == 0) out[bidx*NOUT + n] = acc + cb2[n];
    }
}

extern "C" void kernel_launch(void* const* d_in, const int* in_sizes, int n_in,
                              void* d_out, int out_size, void* d_ws, size_t ws_size,
                              hipStream_t stream) {
    const int*   tokens   = (const int*)  d_in[0];
    const float* emb      = (const float*)d_in[1];
    const float* ln_g     = (const float*)d_in[2];
    const float* ln_b     = (const float*)d_in[3];
    const float* ctrl_w1  = (const float*)d_in[4];
    const float* ctrl_b1  = (const float*)d_in[5];
    const float* ctrl_w2  = (const float*)d_in[6];
    const float* ctrl_b2  = (const float*)d_in[7];
    const float* gate_w   = (const float*)d_in[8];
    const float* gate_b   = (const float*)d_in[9];
    const float* assign_w = (const float*)d_in[10];
    const float* assign_b = (const float*)d_in[11];
    const float* nov_w    = (const float*)d_in[12];
    const float* nov_b    = (const float*)d_in[13];
    const float* relax_w  = (const float*)d_in[14];
    const float* relax_b  = (const float*)d_in[15];
    const float* cc_w     = (const float*)d_in[16];
    const float* cc_b     = (const float*)d_in[17];
    const float* cs_w     = (const float*)d_in[18];
    const float* cs_b     = (const float*)d_in[19];
    const float* md_w     = (const float*)d_in[20];
    const float* md_b     = (const float*)d_in[21];
    const float* att_w    = (const float*)d_in[22];
    const float* att_b    = (const float*)d_in[23];
    const float* cls_w1   = (const float*)d_in[24];
    const float* cls_b1   = (const float*)d_in[25];
    const float* cls_w2   = (const float*)d_in[26];
    const float* cls_b2   = (const float*)d_in[27];
    float* out = (float*)d_out;

    hipLaunchKernelGGL(cfrm_kernel, dim3(NB), dim3(512), 0, stream,
                       tokens, emb, ln_g, ln_b,
                       ctrl_w1, ctrl_b1, ctrl_w2, ctrl_b2,
                       gate_w, gate_b, assign_w, assign_b,
                       nov_w, nov_b, relax_w, relax_b,
                       cc_w, cc_b, cs_w, cs_b, md_w, md_b,
                       att_w, att_b, cls_w1, cls_b1, cls_w2, cls_b2,
                       out);
}